// Round 6
// baseline (165.018 us; speedup 1.0000x reference)
//
#include <hip/hip_runtime.h>
#include <hip/hip_bf16.h>

// MiniEq2Net round 6. B=8, n=256, nin=16, C=32, DH=128.  Two launches.
//
//   h1[c,i,j] = relu( Q[c,i,j] + R1[c,i] + T1[c] + (i==j)*Dg1[c,i] )
//     Q = p[pos x 16d] . A1w[16d x 32c],  p_d = x[i,d]*x[j,d]  (symmetric)
//   out2(i,j)[s] = sum_c hA[c]W0[c,s] + hB[c]W1[c,s] + bcast  (u/v trick)
//   g[b,s] = sum_ij relu(out2); MLP 32->128->128->1.
//
// Round-6 changes vs round 4 (119 us, passing):
//  - A-fragments for the layer-1 MFMA built DIRECTLY in registers from two
//    aligned float4 LDS reads of x (pos=g*16+m -> ti=g, tj=m): no p-build
//    stage, no sP buffer, and kC's strip loop is now barrier-free
//    (16 barriers -> 0); kD loses one barrier per unit.
//  - Decoder MLP fused into kD via last-block-done pattern (per-batch atomic
//    counter + threadfence; counter/G zeroed by kC, stream-ordered).
//    3 launches -> 2, k5's 8-block latency kernel gone.

#define NB 8
#define NN 256
#define ND 16
#define NC 32
#define W1S 160
#define W2S 160
#define XP 20   // padded x row pitch (floats): 80 B, 16B-aligned rows

using bf16x8 = __attribute__((ext_vector_type(8))) __bf16;
using f32x4  = __attribute__((ext_vector_type(4))) float;

#define MFMA(a, b, c) __builtin_amdgcn_mfma_f32_16x16x32_bf16((a), (b), (c), 0, 0, 0)

// Build layer-1 A-fragment: av[j'] = xi[q8+j'] * xj[q8+j'] for quad<2, else 0.
__device__ __forceinline__ bf16x8 make_av(const float* xi, const float* xj, int quad)
{
    bf16x8 av;
    if (quad < 2) {
        const float4* a = (const float4*)(xi + quad * 8);
        const float4* b = (const float4*)(xj + quad * 8);
        float4 a0 = a[0], a1 = a[1], b0 = b[0], b1 = b[1];
        av[0] = (__bf16)(a0.x * b0.x); av[1] = (__bf16)(a0.y * b0.y);
        av[2] = (__bf16)(a0.z * b0.z); av[3] = (__bf16)(a0.w * b0.w);
        av[4] = (__bf16)(a1.x * b1.x); av[5] = (__bf16)(a1.y * b1.y);
        av[6] = (__bf16)(a1.z * b1.z); av[7] = (__bf16)(a1.w * b1.w);
    } else {
        #pragma unroll
        for (int j = 0; j < 8; ++j) av[j] = (__bf16)0.f;
    }
    return av;
}

// ---------------- kC: 8-row tiles; layer-1 row/diag/total sums + CD2/CR2 ----
// grid (32, NB), 256 threads.
__global__ __launch_bounds__(256) void kC_rows(
    const float* __restrict__ x, const float* __restrict__ W1,
    const float* __restrict__ b1, const float* __restrict__ W2,
    float* __restrict__ T1g, float* __restrict__ R1, float* __restrict__ Dg1,
    float* __restrict__ TotP, float* __restrict__ CD2, float* __restrict__ CR2,
    float* __restrict__ G, unsigned int* __restrict__ cnt)
{
    const int TI = blockIdx.x, b = blockIdx.y, t = threadIdx.x;
    __shared__ __align__(16) float  sX[NN][XP];       // 20 KB
    __shared__ __align__(16) __bf16 sBQ[NC][48];      // 3 KB
    __shared__ float part[16][ND + 1];
    __shared__ float sS[ND], sT1[NC];
    __shared__ float sRT[8][NC], sDgL[8][NC], sRow[8][NC], sDiag[8][NC];

    const float* xg = x + b * NN * ND;
    #pragma unroll
    for (int kk = 0; kk < 16; ++kk) {
        int idx = t + kk * 256;
        sX[idx >> 4][idx & 15] = xg[idx];
    }
    #pragma unroll
    for (int kk = 0; kk < 2; ++kk) {   // A1w B-table (k<16), rest zero
        int idx = t + kk * 256; int c = idx >> 4, k = idx & 15;
        sBQ[c][k] = (__bf16)(W1[(ND + k) * W1S + c * 5 + 0]
                           + W1[(ND + k) * W1S + c * 5 + 1]);
    }
    #pragma unroll
    for (int kk = 0; kk < 4; ++kk) {
        int idx = t + kk * 256;
        sBQ[idx >> 5][16 + (idx & 31)] = (__bf16)0.f;
    }
    if (TI == 0) {   // zero G + counter for kD's last-block pattern
        if (t < NC) G[b * NC + t] = 0.f;
        if (t == NC) cnt[b] = 0u;
    }
    __syncthreads();

    {   // column sums S[d]
        int rr = t >> 4, d = t & 15;
        float p = 0.f;
        #pragma unroll
        for (int k = 0; k < 16; ++k) p += sX[rr + (k << 4)][d];
        part[rr][d] = p;
    }
    __syncthreads();
    if (t < ND) {
        float s = 0.f;
        #pragma unroll
        for (int k = 0; k < 16; ++k) s += part[k][t];
        sS[t] = s;
    }
    __syncthreads();
    if (t < NC) {   // T1
        int c = t; float tt = 0.f;
        #pragma unroll
        for (int d = 0; d < ND; ++d)
            tt += sS[d] * W1[d * W1S + c * 5 + 4]
                + sS[d] * sS[d] * W1[(ND + d) * W1S + c * 5 + 4];
        float v = tt * (1.f / 65536.f) + b1[c];
        sT1[c] = v;
        if (TI == 0) T1g[b * NC + c] = v;
    }
    __syncthreads();
    {   // R1/Dg1 for the 8 tile rows
        int i_l = t >> 5, c = t & 31;
        int gi = TI * 8 + i_l;
        float r = 0.f, dg = 0.f;
        #pragma unroll
        for (int d = 0; d < ND; ++d) {
            float xi = sX[gi][d];
            const float* wa = W1 + d * W1S + c * 5;
            const float* wb = W1 + (ND + d) * W1S + c * 5;
            r  += xi * wa[3] + xi * sS[d] * wb[3];
            dg += xi * (wa[0] + wa[1] + wa[2]) + xi * xi * wb[2];
        }
        r *= (1.f / 256.f);
        R1[(b * NN + gi) * NC + c] = r;
        Dg1[(b * NN + gi) * NC + c] = dg;
        sRT[i_l][c] = sT1[c] + r;
        sDgL[i_l][c] = dg;
    }
    __syncthreads();

    const int ln = t & 63, wv = t >> 6;
    const int m = ln & 15, quad = ln >> 4;
    bf16x8 bq0 = *(const bf16x8*)&sBQ[m][8 * quad];
    bf16x8 bq1 = *(const bf16x8*)&sBQ[m + 16][8 * quad];
    f32x4 zero = {0.f, 0.f, 0.f, 0.f};
    float rs0[4] = {0.f, 0.f, 0.f, 0.f}, rs1[4] = {0.f, 0.f, 0.f, 0.f};
    const int i_base = TI * 8;

    // barrier-free strip loop: A-fragment built in-register from sX
    for (int jg = 0; jg < 8; ++jg) {
        #pragma unroll
        for (int gg = 0; gg < 4; ++gg) {
            int g = wv * 4 + gg;
            int i_l = g >> 1;
            int gi = i_base + i_l;
            int jrow = jg * 32 + (g & 1) * 16 + m;
            bf16x8 av = make_av(&sX[gi][0], &sX[jrow][0], quad);
            f32x4 q0 = MFMA(av, bq0, zero);
            f32x4 q1 = MFMA(av, bq1, zero);
            float rt0 = sRT[i_l][m], rt1 = sRT[i_l][m + 16];
            int jb = jg * 32 + (g & 1) * 16 + quad * 4;
            #pragma unroll
            for (int r = 0; r < 4; ++r) {
                float v0 = q0[r] + rt0, v1 = q1[r] + rt1;
                bool dgf = (jb + r == gi);
                if (dgf) { v0 += sDgL[i_l][m]; v1 += sDgL[i_l][m + 16]; }
                float h0 = fmaxf(v0, 0.f), h1 = fmaxf(v1, 0.f);
                if (dgf) { sDiag[i_l][m] = h0; sDiag[i_l][m + 16] = h1; }
                rs0[gg] += h0; rs1[gg] += h1;
            }
        }
    }
    float a0 = rs0[0] + rs0[1], a1 = rs0[2] + rs0[3];
    float b0 = rs1[0] + rs1[1], b1v = rs1[2] + rs1[3];
    a0 += __shfl_down(a0, 32, 64);  a0 += __shfl_down(a0, 16, 64);
    a1 += __shfl_down(a1, 32, 64);  a1 += __shfl_down(a1, 16, 64);
    b0 += __shfl_down(b0, 32, 64);  b0 += __shfl_down(b0, 16, 64);
    b1v += __shfl_down(b1v, 32, 64); b1v += __shfl_down(b1v, 16, 64);
    __syncthreads();
    if (ln < 16) {
        sRow[wv * 2][ln] = a0;       sRow[wv * 2 + 1][ln] = a1;
        sRow[wv * 2][ln + 16] = b0;  sRow[wv * 2 + 1][ln + 16] = b1v;
    }
    __syncthreads();
    if (t < NC) {
        float s = 0.f;
        #pragma unroll
        for (int i = 0; i < 8; ++i) s += sRow[i][t];
        TotP[TI * (NB * NC) + b * NC + t] = s;
    }
    {
        int i_l = t >> 5, s = t & 31;
        int gi = i_base + i_l;
        float cd = 0.f, cr = 0.f;
        #pragma unroll
        for (int c = 0; c < NC; ++c) {
            cd += sDiag[i_l][c] * W2[c * W2S + s * 5 + 2];
            cr += sRow[i_l][c]  * W2[c * W2S + s * 5 + 3];
        }
        CD2[(b * NN + gi) * NC + s] = cd;
        CR2[(b * NN + gi) * NC + s] = cr * (1.f / 256.f);
    }
}

// ---------------- kD: tile-pair layer1+layer2+reduce; last block runs MLP ---
__global__ __launch_bounds__(256) void kD_main(
    const float* __restrict__ x, const float* __restrict__ W1,
    const float* __restrict__ W2, const float* __restrict__ b2,
    const float* __restrict__ T1g, const float* __restrict__ R1g,
    const float* __restrict__ Dg1g, const float* __restrict__ CD2g,
    const float* __restrict__ CR2g, const float* __restrict__ TotP,
    float* __restrict__ G, unsigned int* __restrict__ cnt,
    const float* __restrict__ D1, const float* __restrict__ db1,
    const float* __restrict__ D2, const float* __restrict__ db2,
    const float* __restrict__ D3, const float* __restrict__ db3,
    float* __restrict__ out)
{
    const int b = blockIdx.y, t = threadIdx.x;
    int TI = 0, rem = blockIdx.x;
    while (rem >= 16 - TI) { rem -= 16 - TI; ++TI; }
    const int TJ = TI + rem;
    const bool diagblk = (TI == TJ), mirror = !diagblk;

    __shared__ __align__(16) __bf16 sU[NN][40];
    __shared__ __align__(16) __bf16 sV[NN][40];
    __shared__ __align__(16) __bf16 sBQ[NC][48];
    __shared__ __align__(16) __bf16 sWp[NC][40];
    __shared__ __align__(16) __bf16 sWm[NC][40];
    __shared__ __align__(16) float sXI[16][XP], sXJ[16][XP];
    __shared__ float sR1I[16][NC], sR1J[16][NC];
    __shared__ float sCR2I[16][NC], sCR2J[16][NC];
    __shared__ float sCD2I[16][NC], sDgI[16][NC];
    __shared__ float sT1[NC], sTot[NC], sCT2[NC];
    __shared__ float red[4][NC];
    __shared__ float mA[NC], mH[128], mR[2];
    __shared__ bool  lastFlag;

    { int r = t >> 4, d = t & 15;
      sXI[r][d] = x[(b * NN + TI * 16 + r) * ND + d];
      sXJ[r][d] = x[(b * NN + TJ * 16 + r) * ND + d]; }
    #pragma unroll
    for (int kk = 0; kk < 2; ++kk) {
      int idx = t + kk * 256; int r = idx >> 5, c = idx & 31;
      sR1I[r][c]  = R1g [(b * NN + TI * 16 + r) * NC + c];
      sR1J[r][c]  = R1g [(b * NN + TJ * 16 + r) * NC + c];
      sCR2I[r][c] = CR2g[(b * NN + TI * 16 + r) * NC + c];
      sCR2J[r][c] = CR2g[(b * NN + TJ * 16 + r) * NC + c];
      sCD2I[r][c] = CD2g[(b * NN + TI * 16 + r) * NC + c];
      sDgI[r][c]  = Dg1g[(b * NN + TI * 16 + r) * NC + c];
    }
    #pragma unroll
    for (int kk = 0; kk < 2; ++kk) {
      int idx = t + kk * 256; int c = idx >> 4, k = idx & 15;
      sBQ[c][k] = (__bf16)(W1[(ND + k) * W1S + c * 5 + 0]
                         + W1[(ND + k) * W1S + c * 5 + 1]);
    }
    #pragma unroll
    for (int kk = 0; kk < 4; ++kk) {
      int idx = t + kk * 256;
      sBQ[idx >> 5][16 + (idx & 31)] = (__bf16)0.f;
    }
    #pragma unroll
    for (int kk = 0; kk < 4; ++kk) {
      int idx = t + kk * 256; int s = idx >> 5, c = idx & 31;
      float w0 = W2[c * W2S + s * 5 + 0], w1 = W2[c * W2S + s * 5 + 1];
      sWp[s][c] = (__bf16)((w0 + w1) * 0.5f);
      sWm[s][c] = (__bf16)((w0 - w1) * 0.5f);
    }
    if (t < NC) {
      sT1[t] = T1g[b * NC + t];
      float tot = 0.f;
      #pragma unroll
      for (int k = 0; k < 32; ++k) tot += TotP[k * (NB * NC) + b * NC + t];
      sTot[t] = tot;
    }
    __syncthreads();
    if (t < NC) {   // CT2 (consumed after next barrier)
      float ct = 0.f;
      #pragma unroll
      for (int c = 0; c < NC; ++c) ct += sTot[c] * W2[c * W2S + t * 5 + 4];
      sCT2[t] = ct * (1.f / 65536.f) + b2[t];
    }

    const int ln = t & 63, wv = t >> 6;
    const int m = ln & 15, quad = ln >> 4;
    const int c0 = m, c1 = m + 16;
    f32x4 zero = {0.f, 0.f, 0.f, 0.f};

    {   // layer-1: h = relu(Q + T1 + R1); direct-register A-fragments
        bf16x8 bq0 = *(const bf16x8*)&sBQ[c0][8 * quad];
        bf16x8 bq1 = *(const bf16x8*)&sBQ[c1][8 * quad];
        float t10 = sT1[c0], t11 = sT1[c1];
        #pragma unroll
        for (int gg = 0; gg < 4; ++gg) {
            int g = wv * 4 + gg;              // pos = g*16+m -> ti=g, tj=m
            bf16x8 av = make_av(&sXI[g][0], &sXJ[m][0], quad);
            f32x4 q0 = MFMA(av, bq0, zero);
            f32x4 q1 = MFMA(av, bq1, zero);
            float r1i0 = sR1I[g][c0] + t10, r1i1 = sR1I[g][c1] + t11;
            #pragma unroll
            for (int r = 0; r < 4; ++r) {
                int tj = quad * 4 + r;
                float a0 = q0[r] + r1i0, b0 = q0[r] + sR1J[tj][c0] + t10;
                float a1v = q1[r] + r1i1, b1v = q1[r] + sR1J[tj][c1] + t11;
                if (diagblk && tj == g) {
                    a0 += sDgI[g][c0]; b0 = a0;
                    a1v += sDgI[g][c1]; b1v = a1v;
                }
                float hA0 = fmaxf(a0, 0.f), hB0 = fmaxf(b0, 0.f);
                float hA1 = fmaxf(a1v, 0.f), hB1 = fmaxf(b1v, 0.f);
                int pos = g * 16 + tj;
                sU[pos][c0] = (__bf16)(hA0 + hB0);
                sV[pos][c0] = (__bf16)(hA0 - hB0);
                sU[pos][c1] = (__bf16)(hA1 + hB1);
                sV[pos][c1] = (__bf16)(hA1 - hB1);
            }
        }
    }
    __syncthreads();

    // layer-2: a1 = U.Wp + V.Wm + bcast_i, a2 = U.Wp - V.Wm + bcast_j
    const int s0 = m, s1 = m + 16;
    bf16x8 wp0 = *(const bf16x8*)&sWp[s0][8 * quad];
    bf16x8 wp1 = *(const bf16x8*)&sWp[s1][8 * quad];
    bf16x8 wm0 = *(const bf16x8*)&sWm[s0][8 * quad];
    bf16x8 wm1 = *(const bf16x8*)&sWm[s1][8 * quad];
    float ct0 = sCT2[s0], ct1 = sCT2[s1];
    float acc0 = 0.f, acc1 = 0.f;
    #pragma unroll
    for (int gg = 0; gg < 4; ++gg) {
        int g = wv * 4 + gg;
        bf16x8 ua = *(const bf16x8*)&sU[g * 16 + m][8 * quad];
        bf16x8 va = *(const bf16x8*)&sV[g * 16 + m][8 * quad];
        f32x4 P0 = MFMA(ua, wp0, zero);
        f32x4 M0 = MFMA(va, wm0, zero);
        f32x4 P1 = MFMA(ua, wp1, zero);
        f32x4 M1 = MFMA(va, wm1, zero);
        float crI0 = sCR2I[g][s0] + ct0, crI1 = sCR2I[g][s1] + ct1;
        float cd0 = sCD2I[g][s0], cd1 = sCD2I[g][s1];
        #pragma unroll
        for (int r = 0; r < 4; ++r) {
            int tj = quad * 4 + r;
            float a1 = P0[r] + M0[r] + crI0;
            float a2 = P0[r] - M0[r] + sCR2J[tj][s0] + ct0;
            float e1 = P1[r] + M1[r] + crI1;
            float e2 = P1[r] - M1[r] + sCR2J[tj][s1] + ct1;
            if (diagblk && tj == g) { a1 += cd0; e1 += cd1; }
            acc0 += fmaxf(a1, 0.f); acc1 += fmaxf(e1, 0.f);
            if (mirror) { acc0 += fmaxf(a2, 0.f); acc1 += fmaxf(e2, 0.f); }
        }
    }
    acc0 += __shfl_down(acc0, 32, 64); acc0 += __shfl_down(acc0, 16, 64);
    acc1 += __shfl_down(acc1, 32, 64); acc1 += __shfl_down(acc1, 16, 64);
    __syncthreads();
    if (ln < 16) { red[wv][ln] = acc0; red[wv][ln + 16] = acc1; }
    __syncthreads();
    if (t < NC)
        atomicAdd(&G[b * NC + t], red[0][t] + red[1][t] + red[2][t] + red[3][t]);

    // ---- last-block-done: final block for this batch runs the decoder MLP
    __threadfence();
    if (t == 0) {
        unsigned int old = atomicAdd(&cnt[b], 1u);
        lastFlag = (old == 135u);
    }
    __syncthreads();
    if (!lastFlag) return;
    __threadfence();

    if (t < NC)
        mA[t] = fmaxf(__hip_atomic_load(&G[b * NC + t], __ATOMIC_RELAXED,
                                        __HIP_MEMORY_SCOPE_AGENT), 0.f);
    __syncthreads();
    if (t < 128) {
        float acc = db1[t];
        #pragma unroll
        for (int s = 0; s < NC; ++s) acc += mA[s] * D1[s * 128 + t];
        mH[t] = fmaxf(acc, 0.f);
    }
    __syncthreads();
    if (t < 128) {
        float acc2 = db2[t];
        #pragma unroll 8
        for (int u = 0; u < 128; ++u) acc2 += mH[u] * D2[u * 128 + t];
        float h3 = fmaxf(acc2, 0.f);
        float v = h3 * D3[t];
        #pragma unroll
        for (int off = 32; off > 0; off >>= 1) v += __shfl_down(v, off, 64);
        if ((t & 63) == 0) mR[t >> 6] = v;
    }
    __syncthreads();
    if (t == 0) out[b] = mR[0] + mR[1] + db3[0];
}

extern "C" void kernel_launch(void* const* d_in, const int* in_sizes, int n_in,
                              void* d_out, int out_size, void* d_ws, size_t ws_size,
                              hipStream_t stream)
{
    const float* x   = (const float*)d_in[0];
    const float* W1  = (const float*)d_in[1];
    const float* b1  = (const float*)d_in[2];
    const float* W2  = (const float*)d_in[3];
    const float* b2  = (const float*)d_in[4];
    const float* D1  = (const float*)d_in[5];
    const float* db1 = (const float*)d_in[6];
    const float* D2  = (const float*)d_in[7];
    const float* db2 = (const float*)d_in[8];
    const float* D3  = (const float*)d_in[9];
    const float* db3 = (const float*)d_in[10];
    float* out = (float*)d_out;

    float* w = (float*)d_ws;
    float* pT1   = w; w += NB * NC;          // 256
    float* pTotP = w; w += 32 * NB * NC;     // 8192
    float* pG    = w; w += NB * NC;          // 256
    unsigned int* pCnt = (unsigned int*)w; w += NB;
    float* pR1   = w; w += NB * NN * NC;     // 65536
    float* pDg1  = w; w += NB * NN * NC;
    float* pCD2  = w; w += NB * NN * NC;
    float* pCR2  = w; w += NB * NN * NC;

    hipLaunchKernelGGL(kC_rows, dim3(32, NB), dim3(256), 0, stream,
                       x, W1, b1, W2, pT1, pR1, pDg1, pTotP, pCD2, pCR2,
                       pG, pCnt);
    hipLaunchKernelGGL(kD_main, dim3(136, NB), dim3(256), 0, stream,
                       x, W1, W2, b2, pT1, pR1, pDg1, pCD2, pCR2, pTotP,
                       pG, pCnt, D1, db1, D2, db2, D3, db3, out);
}

// Round 7
// 115.547 us; speedup vs baseline: 1.4281x; 1.4281x over previous
//
#include <hip/hip_runtime.h>
#include <hip/hip_bf16.h>

// MiniEq2Net round 7. B=8, n=256, nin=16, C=32, DH=128.  Three launches.
//
//   h1[c,i,j] = relu( Q[c,i,j] + R1[c,i] + T1[c] + (i==j)*Dg1[c,i] )
//     Q = p[pos x 16d] . A1w[16d x 32c],  p_d = x[i,d]*x[j,d]  (symmetric)
//   out2(i,j)[s] = sum_c hA[c]W0[c,s] + hB[c]W1[c,s] + bcast  (u/v trick)
//   g[b,s] = sum_ij relu(out2); MLP 32->128->128->1.
//
// Round-7 changes vs round 6 (165 us; fence-stalled kD at 84.8 us):
//  - Revert tail fusion: no __threadfence/atomics; kD writes GP partials,
//    k5 reduces + MLP (round-4 skeleton).
//  - kD LDS 66 -> ~22 KB: epilogue constants live in REGISTERS loaded from
//    L2-hot global; U/V are PER-WAVE 16-row buffers (consumer rows of group
//    g are produced by the same wave) -> main loop is barrier-free, wave-
//    local s_waitcnt lgkmcnt(0) replaces __syncthreads.
//  - U/V packed as b32 with channel-pair interleave k'=2c/2c+1 (Wp/Wm staged
//    with same K-permutation): conflict-free writes, half the DS ops.
//  - kC: 4 rows/block, grid 64x8=512 (2 blocks/CU); each wave owns one row.

#define NB 8
#define NN 256
#define ND 16
#define NC 32
#define W1S 160   // W1 row stride (floats)
#define W2S 160   // W2 row stride (floats)
#define XP 20     // padded x row pitch (floats), 16B-aligned rows

using bf16x8 = __attribute__((ext_vector_type(8))) __bf16;
using f32x4  = __attribute__((ext_vector_type(4))) float;

#define MFMA(a, b, c) __builtin_amdgcn_mfma_f32_16x16x32_bf16((a), (b), (c), 0, 0, 0)

// wave-local producer->consumer LDS sync: all this wave's ds_writes complete
// before subsequent ds_reads; wave_barriers pin compiler ordering.
#define WAVE_LDS_SYNC() do {                      \
    __builtin_amdgcn_wave_barrier();              \
    __builtin_amdgcn_s_waitcnt(0xc07f); /* lgkmcnt(0) */ \
    __builtin_amdgcn_wave_barrier();              \
} while (0)

// Layer-1 A-fragment: av[j'] = xi[q*8+j'] * xj[q*8+j'] for quad<2, else 0.
__device__ __forceinline__ bf16x8 make_av(const float* xi, const float* xj, int quad)
{
    bf16x8 av;
    if (quad < 2) {
        const float4* a = (const float4*)(xi + quad * 8);
        const float4* b = (const float4*)(xj + quad * 8);
        float4 a0 = a[0], a1 = a[1], b0 = b[0], b1 = b[1];
        av[0] = (__bf16)(a0.x * b0.x); av[1] = (__bf16)(a0.y * b0.y);
        av[2] = (__bf16)(a0.z * b0.z); av[3] = (__bf16)(a0.w * b0.w);
        av[4] = (__bf16)(a1.x * b1.x); av[5] = (__bf16)(a1.y * b1.y);
        av[6] = (__bf16)(a1.z * b1.z); av[7] = (__bf16)(a1.w * b1.w);
    } else {
        #pragma unroll
        for (int j = 0; j < 8; ++j) av[j] = (__bf16)0.f;
    }
    return av;
}

__device__ __forceinline__ unsigned pack2(float lo, float hi)
{
    union { __bf16 b[2]; unsigned u; } p;
    p.b[0] = (__bf16)lo; p.b[1] = (__bf16)hi;
    return p.u;
}

// ---------------- kC: 4-row tiles; layer-1 row/diag/total sums + CD2/CR2 ----
// grid (64, NB), 256 threads. Each wave owns row i_l = wv.
__global__ __launch_bounds__(256) void kC_rows(
    const float* __restrict__ x, const float* __restrict__ W1,
    const float* __restrict__ b1, const float* __restrict__ W2,
    float* __restrict__ T1g, float* __restrict__ R1, float* __restrict__ Dg1,
    float* __restrict__ TotP, float* __restrict__ CD2, float* __restrict__ CR2)
{
    const int TI = blockIdx.x, b = blockIdx.y, t = threadIdx.x;
    __shared__ __align__(16) float  sX[NN][XP];       // 20 KB
    __shared__ __align__(16) __bf16 sBQ[NC][48];      // 3 KB
    __shared__ float part[16][ND + 1];
    __shared__ float sS[ND], sT1[NC];
    __shared__ float sRT[4][NC], sDgL[4][NC], sRow[4][NC], sDiag[4][NC];

    const float* xg = x + b * NN * ND;
    #pragma unroll
    for (int kk = 0; kk < 16; ++kk) {
        int idx = t + kk * 256;
        sX[idx >> 4][idx & 15] = xg[idx];
    }
    #pragma unroll
    for (int kk = 0; kk < 2; ++kk) {   // A1w B-table (k<16), rest zero
        int idx = t + kk * 256; int c = idx >> 4, k = idx & 15;
        sBQ[c][k] = (__bf16)(W1[(ND + k) * W1S + c * 5 + 0]
                           + W1[(ND + k) * W1S + c * 5 + 1]);
    }
    #pragma unroll
    for (int kk = 0; kk < 4; ++kk) {
        int idx = t + kk * 256;
        sBQ[idx >> 5][16 + (idx & 31)] = (__bf16)0.f;
    }
    __syncthreads();

    {   // column sums S[d]
        int rr = t >> 4, d = t & 15;
        float p = 0.f;
        #pragma unroll
        for (int k = 0; k < 16; ++k) p += sX[rr + (k << 4)][d];
        part[rr][d] = p;
    }
    __syncthreads();
    if (t < ND) {
        float s = 0.f;
        #pragma unroll
        for (int k = 0; k < 16; ++k) s += part[k][t];
        sS[t] = s;
    }
    __syncthreads();
    if (t < NC) {   // T1
        int c = t; float tt = 0.f;
        #pragma unroll
        for (int d = 0; d < ND; ++d)
            tt += sS[d] * W1[d * W1S + c * 5 + 4]
                + sS[d] * sS[d] * W1[(ND + d) * W1S + c * 5 + 4];
        float v = tt * (1.f / 65536.f) + b1[c];
        sT1[c] = v;
        if (TI == 0) T1g[b * NC + c] = v;
    }
    __syncthreads();
    if (t < 128) {   // R1/Dg1 for the 4 tile rows
        int i_l = t >> 5, c = t & 31;
        int gi = TI * 4 + i_l;
        float r = 0.f, dg = 0.f;
        #pragma unroll
        for (int d = 0; d < ND; ++d) {
            float xi = sX[gi][d];
            const float* wa = W1 + d * W1S + c * 5;
            const float* wb = W1 + (ND + d) * W1S + c * 5;
            r  += xi * wa[3] + xi * sS[d] * wb[3];
            dg += xi * (wa[0] + wa[1] + wa[2]) + xi * xi * wb[2];
        }
        r *= (1.f / 256.f);
        R1[(b * NN + gi) * NC + c] = r;
        Dg1[(b * NN + gi) * NC + c] = dg;
        sRT[i_l][c] = sT1[c] + r;
        sDgL[i_l][c] = dg;
    }
    __syncthreads();

    const int ln = t & 63, wv = t >> 6;
    const int m = ln & 15, quad = ln >> 4;
    const int gi = TI * 4 + wv;          // this wave's row
    bf16x8 bq0 = *(const bf16x8*)&sBQ[m][8 * quad];
    bf16x8 bq1 = *(const bf16x8*)&sBQ[m + 16][8 * quad];
    float rt0 = sRT[wv][m], rt1 = sRT[wv][m + 16];
    float dg0 = sDgL[wv][m], dg1 = sDgL[wv][m + 16];
    f32x4 zero = {0.f, 0.f, 0.f, 0.f};
    float rs0 = 0.f, rs1 = 0.f;

    // barrier-free strip loop: 8 strips x 2 halves; A-fragments in-register
    for (int jg = 0; jg < 8; ++jg) {
        #pragma unroll
        for (int gg = 0; gg < 2; ++gg) {
            int jrow = jg * 32 + gg * 16 + m;
            bf16x8 av = make_av(&sX[gi][0], &sX[jrow][0], quad);
            f32x4 q0 = MFMA(av, bq0, zero);
            f32x4 q1 = MFMA(av, bq1, zero);
            int jb = jg * 32 + gg * 16 + quad * 4;
            #pragma unroll
            for (int r = 0; r < 4; ++r) {
                float v0 = q0[r] + rt0, v1 = q1[r] + rt1;
                bool dgf = (jb + r == gi);
                if (dgf) { v0 += dg0; v1 += dg1; }
                float h0 = fmaxf(v0, 0.f), h1 = fmaxf(v1, 0.f);
                if (dgf) { sDiag[wv][m] = h0; sDiag[wv][m + 16] = h1; }
                rs0 += h0; rs1 += h1;
            }
        }
    }
    rs0 += __shfl_down(rs0, 32, 64); rs0 += __shfl_down(rs0, 16, 64);
    rs1 += __shfl_down(rs1, 32, 64); rs1 += __shfl_down(rs1, 16, 64);
    if (ln < 16) { sRow[wv][ln] = rs0; sRow[wv][ln + 16] = rs1; }
    __syncthreads();
    if (t < NC)
        TotP[TI * (NB * NC) + b * NC + t]
            = sRow[0][t] + sRow[1][t] + sRow[2][t] + sRow[3][t];
    if (t < 128) {   // CD2/CR2 for the 4 rows (raw W2, L2-hot)
        int i_l = t >> 5, s = t & 31;
        int gi2 = TI * 4 + i_l;
        float cd = 0.f, cr = 0.f;
        #pragma unroll
        for (int c = 0; c < NC; ++c) {
            cd += sDiag[i_l][c] * W2[c * W2S + s * 5 + 2];
            cr += sRow[i_l][c]  * W2[c * W2S + s * 5 + 3];
        }
        CD2[(b * NN + gi2) * NC + s] = cd;
        CR2[(b * NN + gi2) * NC + s] = cr * (1.f / 256.f);
    }
}

// ---------------- kD: tile-pair layer1+layer2+reduce; per-wave U/V ----------
// grid (136, NB), 256 threads. Epilogue constants in registers from global.
__global__ __launch_bounds__(256) void kD_main(
    const float* __restrict__ x, const float* __restrict__ W1,
    const float* __restrict__ W2, const float* __restrict__ b2,
    const float* __restrict__ T1g, const float* __restrict__ R1g,
    const float* __restrict__ Dg1g, const float* __restrict__ CD2g,
    const float* __restrict__ CR2g, const float* __restrict__ TotP,
    float* __restrict__ GP)
{
    const int b = blockIdx.y, t = threadIdx.x;
    int TI = 0, rem = blockIdx.x;
    while (rem >= 16 - TI) { rem -= 16 - TI; ++TI; }
    const int TJ = TI + rem;
    const bool diagblk = (TI == TJ), mirror = !diagblk;

    __shared__ __align__(16) __bf16 sUw[4][16][40];   // per-wave U (5 KB)
    __shared__ __align__(16) __bf16 sVw[4][16][40];   // per-wave V (5 KB)
    __shared__ __align__(16) __bf16 sBQ[NC][48];
    __shared__ __align__(16) __bf16 sWp[NC][40], sWm[NC][40];  // K-permuted
    __shared__ __align__(16) float sXI[16][XP], sXJ[16][XP];
    __shared__ float sTot[NC], sCT2[NC];
    __shared__ float red[4][NC];

    #pragma unroll
    for (int kk = 0; kk < 2; ++kk) {   // stage x rows
        int idx = t + kk * 256; int rr = idx >> 4, d = idx & 15;
        if (rr < 16) sXI[rr][d] = x[(b * NN + TI * 16 + rr) * ND + d];
        else         sXJ[rr - 16][d] = x[(b * NN + TJ * 16 + rr - 16) * ND + d];
    }
    #pragma unroll
    for (int kk = 0; kk < 2; ++kk) {   // A1w table (k<16), rest zero
        int idx = t + kk * 256; int c = idx >> 4, k = idx & 15;
        sBQ[c][k] = (__bf16)(W1[(ND + k) * W1S + c * 5 + 0]
                           + W1[(ND + k) * W1S + c * 5 + 1]);
    }
    #pragma unroll
    for (int kk = 0; kk < 4; ++kk) {
        int idx = t + kk * 256;
        sBQ[idx >> 5][16 + (idx & 31)] = (__bf16)0.f;
    }
    #pragma unroll
    for (int kk = 0; kk < 4; ++kk) {   // Wp/Wm with K-permutation k'=2c/2c+1
        int idx = t + kk * 256; int s = idx >> 5, kp = idx & 31;
        int c = ((kp & 1) << 4) | (kp >> 1);
        float w0 = W2[c * W2S + s * 5 + 0], w1 = W2[c * W2S + s * 5 + 1];
        sWp[s][kp] = (__bf16)((w0 + w1) * 0.5f);
        sWm[s][kp] = (__bf16)((w0 - w1) * 0.5f);
    }
    if (t < NC) {
        float tot = 0.f;
        #pragma unroll
        for (int k = 0; k < 64; ++k) tot += TotP[k * (NB * NC) + b * NC + t];
        sTot[t] = tot;
    }

    const int ln = t & 63, wv = t >> 6;
    const int m = ln & 15, quad = ln >> 4;

    // layer-1 epilogue constants -> registers (L2-hot global, coalesced by m)
    const float* R1b = R1g + b * NN * NC;
    const float* Dgb = Dg1g + b * NN * NC;
    const float* CDb = CD2g + b * NN * NC;
    const float* CRb = CR2g + b * NN * NC;
    float t10 = T1g[b * NC + m], t11 = T1g[b * NC + m + 16];
    float rti[4][2], dgi[4][2], rtj[4][2];
    #pragma unroll
    for (int gg = 0; gg < 4; ++gg) {
        int rowI = TI * 16 + wv * 4 + gg;
        rti[gg][0] = R1b[rowI * NC + m] + t10;
        rti[gg][1] = R1b[rowI * NC + m + 16] + t11;
        dgi[gg][0] = Dgb[rowI * NC + m];
        dgi[gg][1] = Dgb[rowI * NC + m + 16];
    }
    #pragma unroll
    for (int r = 0; r < 4; ++r) {
        int rowJ = TJ * 16 + quad * 4 + r;
        rtj[r][0] = R1b[rowJ * NC + m] + t10;
        rtj[r][1] = R1b[rowJ * NC + m + 16] + t11;
    }
    __syncthreads();
    if (t < NC) {   // CT2 from sTot
        float ct = 0.f;
        #pragma unroll
        for (int c = 0; c < NC; ++c) ct += sTot[c] * W2[c * W2S + t * 5 + 4];
        sCT2[t] = ct * (1.f / 65536.f) + b2[t];
    }
    __syncthreads();

    float ct0 = sCT2[m], ct1 = sCT2[m + 16];
    float cri[4][2], cdi[4][2], crj[4][2];
    #pragma unroll
    for (int gg = 0; gg < 4; ++gg) {
        int rowI = TI * 16 + wv * 4 + gg;
        cri[gg][0] = CRb[rowI * NC + m] + ct0;
        cri[gg][1] = CRb[rowI * NC + m + 16] + ct1;
        cdi[gg][0] = CDb[rowI * NC + m];
        cdi[gg][1] = CDb[rowI * NC + m + 16];
    }
    #pragma unroll
    for (int r = 0; r < 4; ++r) {
        int rowJ = TJ * 16 + quad * 4 + r;
        crj[r][0] = CRb[rowJ * NC + m] + ct0;
        crj[r][1] = CRb[rowJ * NC + m + 16] + ct1;
    }

    bf16x8 bq0 = *(const bf16x8*)&sBQ[m][8 * quad];
    bf16x8 bq1 = *(const bf16x8*)&sBQ[m + 16][8 * quad];
    bf16x8 wp0 = *(const bf16x8*)&sWp[m][8 * quad];
    bf16x8 wp1 = *(const bf16x8*)&sWp[m + 16][8 * quad];
    bf16x8 wm0 = *(const bf16x8*)&sWm[m][8 * quad];
    bf16x8 wm1 = *(const bf16x8*)&sWm[m + 16][8 * quad];
    __bf16* Uw = &sUw[wv][0][0];
    __bf16* Vw = &sVw[wv][0][0];
    f32x4 zero = {0.f, 0.f, 0.f, 0.f};
    float acc0 = 0.f, acc1 = 0.f;

    // barrier-free main loop: each wave's group g is produced AND consumed
    // by the same wave; WAVE_LDS_SYNC orders the in-wave LDS handoff.
    #pragma unroll
    for (int gg = 0; gg < 4; ++gg) {
        int g = wv * 4 + gg;
        __builtin_amdgcn_wave_barrier();   // keep prior gg's reads before writes
        {   // layer-1: h = relu(Q + T1 + R1 [+Dg]); write packed U/V
            bf16x8 av = make_av(&sXI[g][0], &sXJ[m][0], quad);
            f32x4 q0 = MFMA(av, bq0, zero);
            f32x4 q1 = MFMA(av, bq1, zero);
            #pragma unroll
            for (int r = 0; r < 4; ++r) {
                int tj = quad * 4 + r;
                float a0 = q0[r] + rti[gg][0], b0 = q0[r] + rtj[r][0];
                float a1 = q1[r] + rti[gg][1], b1 = q1[r] + rtj[r][1];
                if (diagblk && tj == g) {
                    a0 += dgi[gg][0]; b0 = a0;
                    a1 += dgi[gg][1]; b1 = a1;
                }
                float hA0 = fmaxf(a0, 0.f), hB0 = fmaxf(b0, 0.f);
                float hA1 = fmaxf(a1, 0.f), hB1 = fmaxf(b1, 0.f);
                *(unsigned*)&Uw[tj * 40 + 2 * m] = pack2(hA0 + hB0, hA1 + hB1);
                *(unsigned*)&Vw[tj * 40 + 2 * m] = pack2(hA0 - hB0, hA1 - hB1);
            }
        }
        WAVE_LDS_SYNC();
        {   // layer-2: a1 = U.Wp + V.Wm + bcast_i, a2 = U.Wp - V.Wm + bcast_j
            bf16x8 ua = *(const bf16x8*)&Uw[m * 40 + 8 * quad];
            bf16x8 va = *(const bf16x8*)&Vw[m * 40 + 8 * quad];
            f32x4 P0 = MFMA(ua, wp0, zero);
            f32x4 M0 = MFMA(va, wm0, zero);
            f32x4 P1 = MFMA(ua, wp1, zero);
            f32x4 M1 = MFMA(va, wm1, zero);
            #pragma unroll
            for (int r = 0; r < 4; ++r) {
                int tj = quad * 4 + r;
                float a1v = P0[r] + M0[r] + cri[gg][0];
                float a2v = P0[r] - M0[r] + crj[r][0];
                float e1 = P1[r] + M1[r] + cri[gg][1];
                float e2 = P1[r] - M1[r] + crj[r][1];
                if (diagblk && tj == g) { a1v += cdi[gg][0]; e1 += cdi[gg][1]; }
                acc0 += fmaxf(a1v, 0.f); acc1 += fmaxf(e1, 0.f);
                if (mirror) { acc0 += fmaxf(a2v, 0.f); acc1 += fmaxf(e2, 0.f); }
            }
        }
    }

    acc0 += __shfl_down(acc0, 32, 64); acc0 += __shfl_down(acc0, 16, 64);
    acc1 += __shfl_down(acc1, 32, 64); acc1 += __shfl_down(acc1, 16, 64);
    if (ln < 16) { red[wv][ln] = acc0; red[wv][ln + 16] = acc1; }
    __syncthreads();
    if (t < NC)
        GP[blockIdx.x * (NB * NC) + b * NC + t]
            = red[0][t] + red[1][t] + red[2][t] + red[3][t];
}

// ---------------- k5: reduce GP (136 partials) + MLP 32->128->128->1 --------
__global__ __launch_bounds__(128) void k5_mlp(
    const float* __restrict__ GP, const float* __restrict__ D1,
    const float* __restrict__ db1, const float* __restrict__ D2,
    const float* __restrict__ db2, const float* __restrict__ D3,
    const float* __restrict__ db3, float* __restrict__ out)
{
    int b = blockIdx.x, t = threadIdx.x;
    __shared__ float sGp[4][NC], a[NC], h2s[128], r2[2];
    {
        int q = t >> 5, s = t & 31;
        float p = 0.f;
        for (int k = q; k < 136; k += 4) p += GP[k * (NB * NC) + b * NC + s];
        sGp[q][s] = p;
    }
    __syncthreads();
    if (t < NC) a[t] = fmaxf(sGp[0][t] + sGp[1][t] + sGp[2][t] + sGp[3][t], 0.f);
    __syncthreads();
    float acc = db1[t];
    #pragma unroll
    for (int s = 0; s < NC; ++s) acc += a[s] * D1[s * 128 + t];
    float h2 = fmaxf(acc, 0.f);
    h2s[t] = h2;
    __syncthreads();
    float acc2 = db2[t];
    #pragma unroll 8
    for (int u = 0; u < 128; ++u) acc2 += h2s[u] * D2[u * 128 + t];
    float h3 = fmaxf(acc2, 0.f);
    float v = h3 * D3[t];
    #pragma unroll
    for (int off = 32; off > 0; off >>= 1) v += __shfl_down(v, off, 64);
    if ((t & 63) == 0) r2[t >> 6] = v;
    __syncthreads();
    if (t == 0) out[b] = r2[0] + r2[1] + db3[0];
}

extern "C" void kernel_launch(void* const* d_in, const int* in_sizes, int n_in,
                              void* d_out, int out_size, void* d_ws, size_t ws_size,
                              hipStream_t stream)
{
    const float* x   = (const float*)d_in[0];
    const float* W1  = (const float*)d_in[1];
    const float* b1  = (const float*)d_in[2];
    const float* W2  = (const float*)d_in[3];
    const float* b2  = (const float*)d_in[4];
    const float* D1  = (const float*)d_in[5];
    const float* db1 = (const float*)d_in[6];
    const float* D2  = (const float*)d_in[7];
    const float* db2 = (const float*)d_in[8];
    const float* D3  = (const float*)d_in[9];
    const float* db3 = (const float*)d_in[10];
    float* out = (float*)d_out;

    float* w = (float*)d_ws;
    float* pT1   = w; w += NB * NC;          // 256
    float* pTotP = w; w += 64 * NB * NC;     // 16384
    float* pGP   = w; w += 136 * NB * NC;    // 34816
    float* pR1   = w; w += NB * NN * NC;     // 65536
    float* pDg1  = w; w += NB * NN * NC;
    float* pCD2  = w; w += NB * NN * NC;
    float* pCR2  = w; w += NB * NN * NC;

    hipLaunchKernelGGL(kC_rows, dim3(64, NB), dim3(256), 0, stream,
                       x, W1, b1, W2, pT1, pR1, pDg1, pTotP, pCD2, pCR2);
    hipLaunchKernelGGL(kD_main, dim3(136, NB), dim3(256), 0, stream,
                       x, W1, W2, b2, pT1, pR1, pDg1, pCD2, pCR2, pTotP, pGP);
    hipLaunchKernelGGL(k5_mlp, dim3(NB), dim3(128), 0, stream,
                       pGP, D1, db1, D2, db2, D3, db3, out);
}

// Round 8
// 112.607 us; speedup vs baseline: 1.4654x; 1.0261x over previous
//
#include <hip/hip_runtime.h>
#include <hip/hip_bf16.h>

// MiniEq2Net round 8. B=8, n=256, nin=16, C=32, DH=128.  Three launches.
//
//   h1[c,i,j] = relu( Q[c,i,j] + R1[c,i] + T1[c] + (i==j)*Dg1[c,i] )
//     Q = p[pos x 16d] . A1w[16d x 32c],  p_d = x[i,d]*x[j,d]  (symmetric)
//   out2(i,j)[s] = sum_c hA[c]W0[c,s] + hB[c]W1[c,s] + bcast  (u/v trick)
//   g[b,s] = sum_ij relu(out2); MLP 32->128->128->1.
//
// Round-8 changes vs round 7 (115.5 us, passing):
//  - kC: T1 folded into the R1/Dg1 d-loop (wa[4]/wb[4] share cache lines
//    with wa[3]/wb[3]) -> one fewer section + one fewer __syncthreads;
//    float4 x->LDS staging.
//  - kD: single preamble barrier. Wave 0 does TotP->sTot->sCT2 with a
//    wave-local lgkmcnt(0) handoff; all epilogue-constant global loads
//    issued pre-barrier; ct folded in post-barrier. float4 x staging.
//  - k5: 256 threads, 8-way GP reduction.

#define NB 8
#define NN 256
#define ND 16
#define NC 32
#define W1S 160   // W1 row stride (floats)
#define W2S 160   // W2 row stride (floats)
#define XP 20     // padded x row pitch (floats), 16B-aligned rows

using bf16x8 = __attribute__((ext_vector_type(8))) __bf16;
using f32x4  = __attribute__((ext_vector_type(4))) float;

#define MFMA(a, b, c) __builtin_amdgcn_mfma_f32_16x16x32_bf16((a), (b), (c), 0, 0, 0)

// wave-local producer->consumer LDS sync
#define WAVE_LDS_SYNC() do {                      \
    __builtin_amdgcn_wave_barrier();              \
    __builtin_amdgcn_s_waitcnt(0xc07f); /* lgkmcnt(0) */ \
    __builtin_amdgcn_wave_barrier();              \
} while (0)

// Layer-1 A-fragment: av[j'] = xi[q*8+j'] * xj[q*8+j'] for quad<2, else 0.
__device__ __forceinline__ bf16x8 make_av(const float* xi, const float* xj, int quad)
{
    bf16x8 av;
    if (quad < 2) {
        const float4* a = (const float4*)(xi + quad * 8);
        const float4* b = (const float4*)(xj + quad * 8);
        float4 a0 = a[0], a1 = a[1], b0 = b[0], b1 = b[1];
        av[0] = (__bf16)(a0.x * b0.x); av[1] = (__bf16)(a0.y * b0.y);
        av[2] = (__bf16)(a0.z * b0.z); av[3] = (__bf16)(a0.w * b0.w);
        av[4] = (__bf16)(a1.x * b1.x); av[5] = (__bf16)(a1.y * b1.y);
        av[6] = (__bf16)(a1.z * b1.z); av[7] = (__bf16)(a1.w * b1.w);
    } else {
        #pragma unroll
        for (int j = 0; j < 8; ++j) av[j] = (__bf16)0.f;
    }
    return av;
}

__device__ __forceinline__ unsigned pack2(float lo, float hi)
{
    union { __bf16 b[2]; unsigned u; } p;
    p.b[0] = (__bf16)lo; p.b[1] = (__bf16)hi;
    return p.u;
}

// ---------------- kC: 4-row tiles; layer-1 row/diag/total sums + CD2/CR2 ----
// grid (64, NB), 256 threads. Each wave owns row i_l = wv.
__global__ __launch_bounds__(256) void kC_rows(
    const float* __restrict__ x, const float* __restrict__ W1,
    const float* __restrict__ b1, const float* __restrict__ W2,
    float* __restrict__ T1g, float* __restrict__ R1, float* __restrict__ Dg1,
    float* __restrict__ TotP, float* __restrict__ CD2, float* __restrict__ CR2)
{
    const int TI = blockIdx.x, b = blockIdx.y, t = threadIdx.x;
    __shared__ __align__(16) float  sX[NN][XP];       // 20 KB
    __shared__ __align__(16) __bf16 sBQ[NC][48];      // 3 KB
    __shared__ float part[16][ND + 1];
    __shared__ float sS[ND];
    __shared__ float sRT[4][NC], sDgL[4][NC], sRow[4][NC], sDiag[4][NC];

    {   // float4 x staging: 1024 float4s, 4 per thread
        const float4* xg4 = (const float4*)(x + b * NN * ND);
        #pragma unroll
        for (int kk = 0; kk < 4; ++kk) {
            int idx = t + kk * 256;              // float4 index
            int row = idx >> 2, c4 = idx & 3;
            *(float4*)&sX[row][c4 * 4] = xg4[idx];
        }
    }
    #pragma unroll
    for (int kk = 0; kk < 2; ++kk) {   // A1w B-table (k<16), rest zero
        int idx = t + kk * 256; int c = idx >> 4, k = idx & 15;
        sBQ[c][k] = (__bf16)(W1[(ND + k) * W1S + c * 5 + 0]
                           + W1[(ND + k) * W1S + c * 5 + 1]);
    }
    #pragma unroll
    for (int kk = 0; kk < 4; ++kk) {
        int idx = t + kk * 256;
        sBQ[idx >> 5][16 + (idx & 31)] = (__bf16)0.f;
    }
    __syncthreads();

    {   // column sums S[d]
        int rr = t >> 4, d = t & 15;
        float p = 0.f;
        #pragma unroll
        for (int k = 0; k < 16; ++k) p += sX[rr + (k << 4)][d];
        part[rr][d] = p;
    }
    __syncthreads();
    if (t < ND) {
        float s = 0.f;
        #pragma unroll
        for (int k = 0; k < 16; ++k) s += part[k][t];
        sS[t] = s;
    }
    __syncthreads();
    if (t < 128) {   // R1/Dg1/T1 fused for the 4 tile rows
        int i_l = t >> 5, c = t & 31;
        int gi = TI * 4 + i_l;
        float r = 0.f, dg = 0.f, tt = 0.f;
        #pragma unroll
        for (int d = 0; d < ND; ++d) {
            float xi = sX[gi][d], sd = sS[d];
            const float* wa = W1 + d * W1S + c * 5;
            const float* wb = W1 + (ND + d) * W1S + c * 5;
            r  += xi * wa[3] + xi * sd * wb[3];
            dg += xi * (wa[0] + wa[1] + wa[2]) + xi * xi * wb[2];
            tt += sd * wa[4] + sd * sd * wb[4];
        }
        r *= (1.f / 256.f);
        float t1 = tt * (1.f / 65536.f) + b1[c];
        R1[(b * NN + gi) * NC + c] = r;
        Dg1[(b * NN + gi) * NC + c] = dg;
        sRT[i_l][c] = t1 + r;
        sDgL[i_l][c] = dg;
        if (TI == 0 && i_l == 0) T1g[b * NC + c] = t1;
    }
    __syncthreads();

    const int ln = t & 63, wv = t >> 6;
    const int m = ln & 15, quad = ln >> 4;
    const int gi = TI * 4 + wv;          // this wave's row
    bf16x8 bq0 = *(const bf16x8*)&sBQ[m][8 * quad];
    bf16x8 bq1 = *(const bf16x8*)&sBQ[m + 16][8 * quad];
    float rt0 = sRT[wv][m], rt1 = sRT[wv][m + 16];
    float dg0 = sDgL[wv][m], dg1 = sDgL[wv][m + 16];
    f32x4 zero = {0.f, 0.f, 0.f, 0.f};
    float rs0 = 0.f, rs1 = 0.f;

    // barrier-free strip loop: A-fragments in-register from sX
    for (int jg = 0; jg < 8; ++jg) {
        #pragma unroll
        for (int gg = 0; gg < 2; ++gg) {
            int jrow = jg * 32 + gg * 16 + m;
            bf16x8 av = make_av(&sX[gi][0], &sX[jrow][0], quad);
            f32x4 q0 = MFMA(av, bq0, zero);
            f32x4 q1 = MFMA(av, bq1, zero);
            int jb = jg * 32 + gg * 16 + quad * 4;
            #pragma unroll
            for (int r = 0; r < 4; ++r) {
                float v0 = q0[r] + rt0, v1 = q1[r] + rt1;
                bool dgf = (jb + r == gi);
                if (dgf) { v0 += dg0; v1 += dg1; }
                float h0 = fmaxf(v0, 0.f), h1 = fmaxf(v1, 0.f);
                if (dgf) { sDiag[wv][m] = h0; sDiag[wv][m + 16] = h1; }
                rs0 += h0; rs1 += h1;
            }
        }
    }
    rs0 += __shfl_down(rs0, 32, 64); rs0 += __shfl_down(rs0, 16, 64);
    rs1 += __shfl_down(rs1, 32, 64); rs1 += __shfl_down(rs1, 16, 64);
    if (ln < 16) { sRow[wv][ln] = rs0; sRow[wv][ln + 16] = rs1; }
    __syncthreads();
    if (t < NC)
        TotP[TI * (NB * NC) + b * NC + t]
            = sRow[0][t] + sRow[1][t] + sRow[2][t] + sRow[3][t];
    if (t < 128) {   // CD2/CR2 for the 4 rows (raw W2, L2-hot)
        int i_l = t >> 5, s = t & 31;
        int gi2 = TI * 4 + i_l;
        float cd = 0.f, cr = 0.f;
        #pragma unroll
        for (int c = 0; c < NC; ++c) {
            cd += sDiag[i_l][c] * W2[c * W2S + s * 5 + 2];
            cr += sRow[i_l][c]  * W2[c * W2S + s * 5 + 3];
        }
        CD2[(b * NN + gi2) * NC + s] = cd;
        CR2[(b * NN + gi2) * NC + s] = cr * (1.f / 256.f);
    }
}

// ---------------- kD: tile-pair layer1+layer2+reduce; per-wave U/V ----------
// grid (136, NB), 256 threads. Single preamble barrier.
__global__ __launch_bounds__(256) void kD_main(
    const float* __restrict__ x, const float* __restrict__ W1,
    const float* __restrict__ W2, const float* __restrict__ b2,
    const float* __restrict__ T1g, const float* __restrict__ R1g,
    const float* __restrict__ Dg1g, const float* __restrict__ CD2g,
    const float* __restrict__ CR2g, const float* __restrict__ TotP,
    float* __restrict__ GP)
{
    const int b = blockIdx.y, t = threadIdx.x;
    int TI = 0, rem = blockIdx.x;
    while (rem >= 16 - TI) { rem -= 16 - TI; ++TI; }
    const int TJ = TI + rem;
    const bool diagblk = (TI == TJ), mirror = !diagblk;

    __shared__ __align__(16) __bf16 sUw[4][16][40];   // per-wave U
    __shared__ __align__(16) __bf16 sVw[4][16][40];   // per-wave V
    __shared__ __align__(16) __bf16 sBQ[NC][48];
    __shared__ __align__(16) __bf16 sWp[NC][40], sWm[NC][40];  // K-permuted
    __shared__ __align__(16) float sXI[16][XP], sXJ[16][XP];
    __shared__ float sTot[NC], sCT2[NC];
    __shared__ float red[4][NC];

    if (t < 128) {   // float4 x staging: 64 float4s per tile
        const float4* xg4 = (const float4*)(x + b * NN * ND);
        int half = t >> 6, idx = t & 63;      // half 0 -> XI, 1 -> XJ
        int row = idx >> 2, c4 = idx & 3;
        int base = (half ? TJ : TI) * 16;
        float4 v = xg4[(base + row) * 4 + c4];
        float* dst = half ? &sXJ[row][c4 * 4] : &sXI[row][c4 * 4];
        *(float4*)dst = v;
    }
    #pragma unroll
    for (int kk = 0; kk < 2; ++kk) {   // A1w table (k<16), rest zero
        int idx = t + kk * 256; int c = idx >> 4, k = idx & 15;
        sBQ[c][k] = (__bf16)(W1[(ND + k) * W1S + c * 5 + 0]
                           + W1[(ND + k) * W1S + c * 5 + 1]);
    }
    #pragma unroll
    for (int kk = 0; kk < 4; ++kk) {
        int idx = t + kk * 256;
        sBQ[idx >> 5][16 + (idx & 31)] = (__bf16)0.f;
    }
    #pragma unroll
    for (int kk = 0; kk < 4; ++kk) {   // Wp/Wm with K-permutation k'=2c/2c+1
        int idx = t + kk * 256; int s = idx >> 5, kp = idx & 31;
        int c = ((kp & 1) << 4) | (kp >> 1);
        float w0 = W2[c * W2S + s * 5 + 0], w1 = W2[c * W2S + s * 5 + 1];
        sWp[s][kp] = (__bf16)((w0 + w1) * 0.5f);
        sWm[s][kp] = (__bf16)((w0 - w1) * 0.5f);
    }
    if (t < NC) {   // wave 0: TotP reduce -> sTot
        float tot = 0.f;
        #pragma unroll
        for (int k = 0; k < 64; ++k) tot += TotP[k * (NB * NC) + b * NC + t];
        sTot[t] = tot;
    }
    if (t < 64) {   // wave-local handoff: sTot (wave 0) -> sCT2 (wave 0)
        WAVE_LDS_SYNC();
        if (t < NC) {
            float ct = 0.f;
            #pragma unroll
            for (int c = 0; c < NC; ++c) ct += sTot[c] * W2[c * W2S + t * 5 + 4];
            sCT2[t] = ct * (1.f / 65536.f) + b2[t];
        }
    }

    const int ln = t & 63, wv = t >> 6;
    const int m = ln & 15, quad = ln >> 4;

    // epilogue constants -> registers (issued pre-barrier, L2-hot, coalesced)
    const float* R1b = R1g + b * NN * NC;
    const float* Dgb = Dg1g + b * NN * NC;
    const float* CDb = CD2g + b * NN * NC;
    const float* CRb = CR2g + b * NN * NC;
    float t10 = T1g[b * NC + m], t11 = T1g[b * NC + m + 16];
    float rti[4][2], dgi[4][2], rtj[4][2];
    float cri[4][2], cdi[4][2], crj[4][2];
    #pragma unroll
    for (int gg = 0; gg < 4; ++gg) {
        int rowI = TI * 16 + wv * 4 + gg;
        rti[gg][0] = R1b[rowI * NC + m] + t10;
        rti[gg][1] = R1b[rowI * NC + m + 16] + t11;
        dgi[gg][0] = Dgb[rowI * NC + m];
        dgi[gg][1] = Dgb[rowI * NC + m + 16];
        cri[gg][0] = CRb[rowI * NC + m];
        cri[gg][1] = CRb[rowI * NC + m + 16];
        cdi[gg][0] = CDb[rowI * NC + m];
        cdi[gg][1] = CDb[rowI * NC + m + 16];
    }
    #pragma unroll
    for (int r = 0; r < 4; ++r) {
        int rowJ = TJ * 16 + quad * 4 + r;
        rtj[r][0] = R1b[rowJ * NC + m] + t10;
        rtj[r][1] = R1b[rowJ * NC + m + 16] + t11;
        crj[r][0] = CRb[rowJ * NC + m];
        crj[r][1] = CRb[rowJ * NC + m + 16];
    }
    __syncthreads();   // single preamble barrier

    float ct0 = sCT2[m], ct1 = sCT2[m + 16];
    #pragma unroll
    for (int gg = 0; gg < 4; ++gg) { cri[gg][0] += ct0; cri[gg][1] += ct1; }
    #pragma unroll
    for (int r = 0; r < 4; ++r) { crj[r][0] += ct0; crj[r][1] += ct1; }

    bf16x8 bq0 = *(const bf16x8*)&sBQ[m][8 * quad];
    bf16x8 bq1 = *(const bf16x8*)&sBQ[m + 16][8 * quad];
    bf16x8 wp0 = *(const bf16x8*)&sWp[m][8 * quad];
    bf16x8 wp1 = *(const bf16x8*)&sWp[m + 16][8 * quad];
    bf16x8 wm0 = *(const bf16x8*)&sWm[m][8 * quad];
    bf16x8 wm1 = *(const bf16x8*)&sWm[m + 16][8 * quad];
    __bf16* Uw = &sUw[wv][0][0];
    __bf16* Vw = &sVw[wv][0][0];
    f32x4 zero = {0.f, 0.f, 0.f, 0.f};
    float acc0 = 0.f, acc1 = 0.f;

    // barrier-free main loop: per-wave U/V with wave-local LDS handoff
    #pragma unroll
    for (int gg = 0; gg < 4; ++gg) {
        int g = wv * 4 + gg;
        __builtin_amdgcn_wave_barrier();   // keep prior gg's reads before writes
        {   // layer-1: h = relu(Q + T1 + R1 [+Dg]); write packed U/V
            bf16x8 av = make_av(&sXI[g][0], &sXJ[m][0], quad);
            f32x4 q0 = MFMA(av, bq0, zero);
            f32x4 q1 = MFMA(av, bq1, zero);
            #pragma unroll
            for (int r = 0; r < 4; ++r) {
                int tj = quad * 4 + r;
                float a0 = q0[r] + rti[gg][0], b0 = q0[r] + rtj[r][0];
                float a1 = q1[r] + rti[gg][1], b1 = q1[r] + rtj[r][1];
                if (diagblk && tj == g) {
                    a0 += dgi[gg][0]; b0 = a0;
                    a1 += dgi[gg][1]; b1 = a1;
                }
                float hA0 = fmaxf(a0, 0.f), hB0 = fmaxf(b0, 0.f);
                float hA1 = fmaxf(a1, 0.f), hB1 = fmaxf(b1, 0.f);
                *(unsigned*)&Uw[tj * 40 + 2 * m] = pack2(hA0 + hB0, hA1 + hB1);
                *(unsigned*)&Vw[tj * 40 + 2 * m] = pack2(hA0 - hB0, hA1 - hB1);
            }
        }
        WAVE_LDS_SYNC();
        {   // layer-2: a1 = U.Wp + V.Wm + bcast_i, a2 = U.Wp - V.Wm + bcast_j
            bf16x8 ua = *(const bf16x8*)&Uw[m * 40 + 8 * quad];
            bf16x8 va = *(const bf16x8*)&Vw[m * 40 + 8 * quad];
            f32x4 P0 = MFMA(ua, wp0, zero);
            f32x4 M0 = MFMA(va, wm0, zero);
            f32x4 P1 = MFMA(ua, wp1, zero);
            f32x4 M1 = MFMA(va, wm1, zero);
            #pragma unroll
            for (int r = 0; r < 4; ++r) {
                int tj = quad * 4 + r;
                float a1v = P0[r] + M0[r] + cri[gg][0];
                float a2v = P0[r] - M0[r] + crj[r][0];
                float e1 = P1[r] + M1[r] + cri[gg][1];
                float e2 = P1[r] - M1[r] + crj[r][1];
                if (diagblk && tj == g) { a1v += cdi[gg][0]; e1 += cdi[gg][1]; }
                acc0 += fmaxf(a1v, 0.f); acc1 += fmaxf(e1, 0.f);
                if (mirror) { acc0 += fmaxf(a2v, 0.f); acc1 += fmaxf(e2, 0.f); }
            }
        }
    }

    acc0 += __shfl_down(acc0, 32, 64); acc0 += __shfl_down(acc0, 16, 64);
    acc1 += __shfl_down(acc1, 32, 64); acc1 += __shfl_down(acc1, 16, 64);
    if (ln < 16) { red[wv][ln] = acc0; red[wv][ln + 16] = acc1; }
    __syncthreads();
    if (t < NC)
        GP[blockIdx.x * (NB * NC) + b * NC + t]
            = red[0][t] + red[1][t] + red[2][t] + red[3][t];
}

// ---------------- k5: reduce GP (136 partials) + MLP 32->128->128->1 --------
__global__ __launch_bounds__(256) void k5_mlp(
    const float* __restrict__ GP, const float* __restrict__ D1,
    const float* __restrict__ db1, const float* __restrict__ D2,
    const float* __restrict__ db2, const float* __restrict__ D3,
    const float* __restrict__ db3, float* __restrict__ out)
{
    int b = blockIdx.x, t = threadIdx.x;
    __shared__ float sGp[8][NC], a[NC], h2s[128], r2[2];
    {
        int q = t >> 5, s = t & 31;
        float p = 0.f;
        for (int k = q; k < 136; k += 8) p += GP[k * (NB * NC) + b * NC + s];
        sGp[q][s] = p;
    }
    __syncthreads();
    if (t < NC) {
        float s = 0.f;
        #pragma unroll
        for (int q = 0; q < 8; ++q) s += sGp[q][t];
        a[t] = fmaxf(s, 0.f);
    }
    __syncthreads();
    if (t < 128) {
        float acc = db1[t];
        #pragma unroll
        for (int s = 0; s < NC; ++s) acc += a[s] * D1[s * 128 + t];
        h2s[t] = fmaxf(acc, 0.f);
    }
    __syncthreads();
    if (t < 128) {
        float acc2 = db2[t];
        #pragma unroll 8
        for (int u = 0; u < 128; ++u) acc2 += h2s[u] * D2[u * 128 + t];
        float h3 = fmaxf(acc2, 0.f);
        float v = h3 * D3[t];
        #pragma unroll
        for (int off = 32; off > 0; off >>= 1) v += __shfl_down(v, off, 64);
        if ((t & 63) == 0) r2[t >> 6] = v;
    }
    __syncthreads();
    if (t == 0) out[b] = r2[0] + r2[1] + db3[0];
}

extern "C" void kernel_launch(void* const* d_in, const int* in_sizes, int n_in,
                              void* d_out, int out_size, void* d_ws, size_t ws_size,
                              hipStream_t stream)
{
    const float* x   = (const float*)d_in[0];
    const float* W1  = (const float*)d_in[1];
    const float* b1  = (const float*)d_in[2];
    const float* W2  = (const float*)d_in[3];
    const float* b2  = (const float*)d_in[4];
    const float* D1  = (const float*)d_in[5];
    const float* db1 = (const float*)d_in[6];
    const float* D2  = (const float*)d_in[7];
    const float* db2 = (const float*)d_in[8];
    const float* D3  = (const float*)d_in[9];
    const float* db3 = (const float*)d_in[10];
    float* out = (float*)d_out;

    float* w = (float*)d_ws;
    float* pT1   = w; w += NB * NC;          // 256
    float* pTotP = w; w += 64 * NB * NC;     // 16384
    float* pGP   = w; w += 136 * NB * NC;    // 34816
    float* pR1   = w; w += NB * NN * NC;     // 65536
    float* pDg1  = w; w += NB * NN * NC;
    float* pCD2  = w; w += NB * NN * NC;
    float* pCR2  = w; w += NB * NN * NC;

    hipLaunchKernelGGL(kC_rows, dim3(64, NB), dim3(256), 0, stream,
                       x, W1, b1, W2, pT1, pR1, pDg1, pTotP, pCD2, pCR2);
    hipLaunchKernelGGL(kD_main, dim3(136, NB), dim3(256), 0, stream,
                       x, W1, W2, b2, pT1, pR1, pDg1, pCD2, pCR2, pTotP, pGP);
    hipLaunchKernelGGL(k5_mlp, dim3(NB), dim3(256), 0, stream,
                       pGP, D1, db1, D2, db2, D3, db3, out);
}